// Round 7
// baseline (209.461 us; speedup 1.0000x reference)
//
#include <hip/hip_runtime.h>
#include <stdint.h>

#define M_DIM 4096
#define N_DIM 4096
#define K_DIM 4096

typedef int i32x4 __attribute__((ext_vector_type(4)));

// ---- Kernel 1 (fused): blocks 0..4095: x per-row quant; blocks 4096..5119: wmax ----
__global__ void prep_kernel(const float* __restrict__ w,
                            const float* __restrict__ x,
                            unsigned int* __restrict__ out_bits,
                            char* __restrict__ xq,
                            float* __restrict__ xsinv) {
    __shared__ float sred[4];
    if (blockIdx.x < 4096) {
        // ---- x -> int8, per-row scale; xsinv[row] = rowmax/127 ----
        const int row = blockIdx.x;
        const int t = threadIdx.x;
        const float4* xr = (const float4*)(x + (size_t)row * K_DIM);
        float4 v[4];
        float m = 0.f;
        #pragma unroll
        for (int i = 0; i < 4; ++i) {
            v[i] = xr[t * 4 + i];
            m = fmaxf(m, fmaxf(fmaxf(fabsf(v[i].x), fabsf(v[i].y)),
                               fmaxf(fabsf(v[i].z), fabsf(v[i].w))));
        }
        for (int off = 32; off > 0; off >>= 1) m = fmaxf(m, __shfl_xor(m, off));
        if ((t & 63) == 0) sred[t >> 6] = m;
        __syncthreads();
        m = fmaxf(fmaxf(fmaxf(sred[0], sred[1]), fmaxf(sred[2], sred[3])), 1e-30f);
        if (t == 0) xsinv[row] = m * (1.0f / 127.0f);
        const float scale = 127.0f / m;
        int4 o;
        int* op = (int*)&o;
        #pragma unroll
        for (int i = 0; i < 4; ++i) {
            int a = (int)rintf(v[i].x * scale);
            int b = (int)rintf(v[i].y * scale);
            int c = (int)rintf(v[i].z * scale);
            int d = (int)rintf(v[i].w * scale);
            op[i] = (a & 0xff) | ((b & 0xff) << 8) | ((c & 0xff) << 16) | (d << 24);
        }
        *(int4*)(xq + (size_t)row * K_DIM + t * 16) = o;
    } else {
        // ---- wmax = max|W| -> uint bits, one atomic per block ----
        int tid = (blockIdx.x - 4096) * blockDim.x + threadIdx.x;
        const int stride = 1024 * 256;
        const int n4 = (N_DIM * K_DIM) / 4;
        const float4* w4 = (const float4*)w;
        float m = 0.f;
        for (int i = tid; i < n4; i += stride) {
            float4 a = w4[i];
            m = fmaxf(m, fmaxf(fmaxf(fabsf(a.x), fabsf(a.y)), fmaxf(fabsf(a.z), fabsf(a.w))));
        }
        for (int off = 32; off > 0; off >>= 1) m = fmaxf(m, __shfl_xor(m, off));
        if ((threadIdx.x & 63) == 0) sred[threadIdx.x >> 6] = m;
        __syncthreads();
        if (threadIdx.x == 0) {
            m = fmaxf(fmaxf(sred[0], sred[1]), fmaxf(sred[2], sred[3]));
            atomicMax(out_bits, __float_as_uint(m));  // |w|>=0: uint order == float order
        }
    }
}

// ---- Kernel 2: W -> int8 (trunc, exact reference grid) ----
__global__ void wquant_kernel(const float* __restrict__ w,
                              const unsigned int* __restrict__ mb,
                              int* __restrict__ wq4, int n4) {
    const float wscale = 127.0f / __uint_as_float(mb[0]);
    int tid = blockIdx.x * blockDim.x + threadIdx.x;
    int stride = gridDim.x * blockDim.x;
    const float4* w4 = (const float4*)w;
    for (int i = tid; i < n4; i += stride) {
        float4 a = w4[i];
        int w0 = (int)fminf(fmaxf(truncf(a.x * wscale), -127.f), 127.f);
        int w1 = (int)fminf(fmaxf(truncf(a.y * wscale), -127.f), 127.f);
        int w2 = (int)fminf(fmaxf(truncf(a.z * wscale), -127.f), 127.f);
        int w3 = (int)fminf(fmaxf(truncf(a.w * wscale), -127.f), 127.f);
        wq4[i] = (w0 & 0xff) | ((w1 & 0xff) << 8) | ((w2 & 0xff) << 16) | (w3 << 24);
    }
}

// ---- Kernel 3: 256x256 i8 GEMM. A (xq) read DIRECTLY from global (L1/L2-hot) into
// fragments; B (wq) staged in LDS (64KB, double-buffered, XOR-swizzled, conflict-free).
// One barrier per K-tile; MFMA region covers VMEM latency + LDS-B service.
#define BAR()   __builtin_amdgcn_s_barrier()
#define FENCE() __builtin_amdgcn_sched_barrier(0)

#define MFMA_I8(ACC, AF, BF) \
    asm("v_mfma_i32_16x16x64_i8 %0, %1, %2, %0" : "+v"(ACC) : "v"(AF), "v"(BF))

__global__ __launch_bounds__(512, 2) void gemm_i8(
    const char* __restrict__ A,
    const char* __restrict__ B,
    const unsigned int* __restrict__ mb,
    const float* __restrict__ xsinv,
    const float* __restrict__ bias,
    float* __restrict__ C)
{
    __shared__ __align__(16) char sM[65536];   // B only: buf0 @0, buf1 @32768

    int bid = (blockIdx.x & 7) * 32 + (blockIdx.x >> 3);   // XCD-bijective (nwg=256)
    const int bm = bid >> 4;
    const int bn = bid & 15;

    const int t    = threadIdx.x;
    const int wave = t >> 6;
    const int lane = t & 63;
    const int wm   = wave >> 2;     // 0..1
    const int wn   = wave & 3;      // 0..3

    i32x4 acc[2][2][4][2] = {};     // [h][g][mi][ni]

    // B LDS-read bases (swizzle folded: row&7 == lane&7 for all row-blocks used)
    const int chunk = (((lane >> 4) << 4) ^ ((lane & 7) << 4));
    const int lbB0 = ((lane & 15) << 7) + chunk + wn * 4096;
    const int lbB1 = lbB0 ^ 64;

    // B staging: thread t owns linear LDS slot t*16 (+8192 for 2nd 64-row block);
    // source chunk pre-swizzled so LDS[row][c] = SRC[row][c^(row&7)].
    const int srow = t >> 3;
    const int cch  = (t & 7) ^ (srow & 7);
    const char* Bbase = B + (size_t)(bn * 256 + srow) * K_DIM + cch * 16;
    const int wave_lds = wave * 1024;

    // A global fragment base: lane l covers row (…+ l&15), k-bytes (l>>4)*16 within 64B.
    const char* Agbase = A + (size_t)(bm * 256 + wm * 64 + (lane & 15)) * K_DIM
                           + ((lane >> 4) << 4);

#define STAGEB(H, KT, BUF) do {                                                         \
        const char* _s = Bbase + (H) * (128 * K_DIM) + ((KT) << 7);                     \
        char* _d = sM + (BUF) * 32768 + (H) * 16384 + wave_lds;                         \
        __builtin_amdgcn_global_load_lds(                                               \
            (const __attribute__((address_space(1))) void*)_s,                          \
            (__attribute__((address_space(3))) void*)_d, 16, 0, 0);                     \
        __builtin_amdgcn_global_load_lds(                                               \
            (const __attribute__((address_space(1))) void*)(_s + (size_t)64 * K_DIM),   \
            (__attribute__((address_space(3))) void*)(_d + 8192), 16, 0, 0);            \
    } while(0)

    // A-frags for row-half H of K-tile KT: 8 x global_load_dwordx4 (per-lane, L1/L2-hot)
#define LDAG(H, KT, AF) do {                                                            \
        const char* _a = Agbase + (size_t)(H) * (128 * K_DIM) + ((KT) << 7);            \
        _Pragma("unroll") for (int mi = 0; mi < 4; ++mi) {                              \
            AF[mi][0] = *(const i32x4*)(_a + mi * (16 * K_DIM));                        \
            AF[mi][1] = *(const i32x4*)(_a + mi * (16 * K_DIM) + 64);                   \
        }                                                                               \
    } while(0)

#define LDB(G, BUF, BF) do {                                                            \
        _Pragma("unroll") for (int ni = 0; ni < 2; ++ni) {                              \
            BF[ni][0] = *(const i32x4*)(sM + (BUF)*32768 + (G)*16384 + ni*2048 + lbB0); \
            BF[ni][1] = *(const i32x4*)(sM + (BUF)*32768 + (G)*16384 + ni*2048 + lbB1); \
        }                                                                               \
    } while(0)

    // one C-quadrant x K=128: 16 MFMA, kk-outer (8 indep accs between acc reuse)
#define MMAQ(H, G, AF, BF)                                                              \
        _Pragma("unroll") for (int kk = 0; kk < 2; ++kk)                                \
        _Pragma("unroll") for (int mi = 0; mi < 4; ++mi)                                \
        _Pragma("unroll") for (int ni = 0; ni < 2; ++ni)                                \
            MFMA_I8(acc[H][G][mi][ni], AF[mi][kk], BF[ni][kk]);

    // One K-tile TC: A-frags from global, B from LDS buf BUF; stages B K-tile KN -> OBUF.
#define TILE(BUF, OBUF, TC, KN) do {                                                    \
        LDAG(0, TC, af0);                        /* 8 vmem */                           \
        LDAG(1, TC, af1);                        /* 8 vmem */                           \
        LDB(0, BUF, bf0); LDB(1, BUF, bf1);      /* 8 ds_read */                        \
        STAGEB(0, KN, OBUF);                                                            \
        STAGEB(1, KN, OBUF);                     /* 4 gload_lds */                      \
        FENCE();                                                                        \
        __builtin_amdgcn_s_setprio(1);                                                  \
        MMAQ(0, 0, af0, bf0);                                                           \
        MMAQ(0, 1, af0, bf1);                                                           \
        MMAQ(1, 1, af1, bf1);                                                           \
        MMAQ(1, 0, af1, bf0);                                                           \
        __builtin_amdgcn_s_setprio(0);                                                  \
        FENCE();                                                                        \
        asm volatile("s_waitcnt vmcnt(0)");      /* B stages (issued ~2500cy ago) landed */ \
        BAR();                                                                          \
        FENCE();                                                                        \
    } while(0)

    // Prologue: stage B tile 0 -> buf0.
    STAGEB(0, 0, 0);
    STAGEB(1, 0, 0);
    asm volatile("s_waitcnt vmcnt(0)");
    BAR();
    FENCE();

    i32x4 af0[4][2], af1[4][2], bf0[2][2], bf1[2][2];

    for (int it = 0; it < 16; ++it) {
        TILE(0, 1, (2 * it),     (2 * it + 1) & 31);
        TILE(1, 0, (2 * it + 1), (2 * it + 2) & 31);
    }

    const float wdq = __uint_as_float(mb[0]) * (1.0f / 127.0f);

    // Epilogue: D layout (m89): col = lane&15, row = (lane>>4)*4 + reg.
    // C = acc * (wdq * xsinv[row]) + bias[col]
    #pragma unroll
    for (int h = 0; h < 2; ++h)
    #pragma unroll
    for (int mi = 0; mi < 4; ++mi) {
        const int grow0 = bm * 256 + h * 128 + wm * 64 + mi * 16 + (lane >> 4) * 4;
        float rs[4];
        #pragma unroll
        for (int rg = 0; rg < 4; ++rg) rs[rg] = xsinv[grow0 + rg] * wdq;
        #pragma unroll
        for (int g = 0; g < 2; ++g)
        #pragma unroll
        for (int ni = 0; ni < 2; ++ni) {
            const int gcol = bn * 256 + g * 128 + wn * 32 + ni * 16 + (lane & 15);
            const float bv = bias[gcol];
            #pragma unroll
            for (int rg = 0; rg < 4; ++rg)
                C[(size_t)(grow0 + rg) * N_DIM + gcol] =
                    (float)acc[h][g][mi][ni][rg] * rs[rg] + bv;
        }
    }

#undef STAGEB
#undef LDAG
#undef LDB
#undef MMAQ
#undef TILE
}

extern "C" void kernel_launch(void* const* d_in, const int* in_sizes, int n_in,
                              void* d_out, int out_size, void* d_ws, size_t ws_size,
                              hipStream_t stream) {
    const float* x    = (const float*)d_in[0];   // [4096, 4096]
    const float* w    = (const float*)d_in[1];   // [4096, 4096]
    const float* bias = (const float*)d_in[2];   // [4096]
    float* out = (float*)d_out;

    unsigned int* maxbits = (unsigned int*)d_ws;            // [0]=wmax bits
    float* xsinv = (float*)((char*)d_ws + 256);             // [4096]
    char*  xq    = (char*)d_ws + 32768;                     // 16 MB
    char*  wq    = (char*)d_ws + 32768 + (size_t)M_DIM * K_DIM;

    hipMemsetAsync(d_ws, 0, 8, stream);

    const int n4 = (N_DIM * K_DIM) / 4;
    prep_kernel<<<4096 + 1024, 256, 0, stream>>>(w, x, maxbits, xq, xsinv);
    wquant_kernel<<<2048, 256, 0, stream>>>(w, maxbits, (int*)wq, n4);

    const int grid = (M_DIM / 256) * (N_DIM / 256);  // 256
    gemm_i8<<<grid, 512, 0, stream>>>(xq, wq, maxbits, xsinv, bias, out);
}

// Round 8
// 136.593 us; speedup vs baseline: 1.5335x; 1.5335x over previous
//
#include <hip/hip_runtime.h>
#include <stdint.h>

#define M_DIM 4096
#define N_DIM 4096
#define K_DIM 4096

typedef int i32x4 __attribute__((ext_vector_type(4)));

// ---- Kernel 1 (fused): blocks 0..4095: x row-max -> xsinv; 4096..5119: wmax atomic ----
__global__ void rowmax_kernel(const float* __restrict__ w,
                              const float* __restrict__ x,
                              unsigned int* __restrict__ out_bits,
                              float* __restrict__ xsinv) {
    __shared__ float sred[4];
    if (blockIdx.x < 4096) {
        const int row = blockIdx.x;
        const int t = threadIdx.x;
        const float4* xr = (const float4*)(x + (size_t)row * K_DIM);
        float m = 0.f;
        #pragma unroll
        for (int i = 0; i < 4; ++i) {
            float4 v = xr[t * 4 + i];
            m = fmaxf(m, fmaxf(fmaxf(fabsf(v.x), fabsf(v.y)),
                               fmaxf(fabsf(v.z), fabsf(v.w))));
        }
        for (int off = 32; off > 0; off >>= 1) m = fmaxf(m, __shfl_xor(m, off));
        if ((t & 63) == 0) sred[t >> 6] = m;
        __syncthreads();
        if (t == 0) {
            m = fmaxf(fmaxf(fmaxf(sred[0], sred[1]), fmaxf(sred[2], sred[3])), 1e-30f);
            xsinv[row] = m * (1.0f / 127.0f);
        }
    } else {
        int tid = (blockIdx.x - 4096) * blockDim.x + threadIdx.x;
        const int stride = 1024 * 256;
        const int n4 = (N_DIM * K_DIM) / 4;
        const float4* w4 = (const float4*)w;
        float m = 0.f;
        for (int i = tid; i < n4; i += stride) {
            float4 a = w4[i];
            m = fmaxf(m, fmaxf(fmaxf(fabsf(a.x), fabsf(a.y)), fmaxf(fabsf(a.z), fabsf(a.w))));
        }
        for (int off = 32; off > 0; off >>= 1) m = fmaxf(m, __shfl_xor(m, off));
        if ((threadIdx.x & 63) == 0) sred[threadIdx.x >> 6] = m;
        __syncthreads();
        if (threadIdx.x == 0) {
            m = fmaxf(fmaxf(sred[0], sred[1]), fmaxf(sred[2], sred[3]));
            atomicMax(out_bits, __float_as_uint(m));  // |w|>=0: uint order == float order
        }
    }
}

__device__ __forceinline__ int pack4(float a, float b, float c, float d, float s) {
    int i0 = (int)rintf(a * s), i1 = (int)rintf(b * s);
    int i2 = (int)rintf(c * s), i3 = (int)rintf(d * s);
    return (i0 & 0xff) | ((i1 & 0xff) << 8) | ((i2 & 0xff) << 16) | (i3 << 24);
}

// ---- Kernel 2 (fused): blocks 0..255: x -> int8 PANELS; 256..2303: W -> int8 row-major ----
// Panel layout: xqp[kb][rb][slot], 1KB per (kb,rb); slot l (16B) = rows rb*16+(l&15),
// k-bytes kb*64 + (l>>4)*16 .. +16  == exactly lane l's mfma_i32_16x16x64_i8 A-fragment.
__global__ void quant_kernel(const float* __restrict__ w,
                             const float* __restrict__ x,
                             const unsigned int* __restrict__ mb,
                             const float* __restrict__ xsinv,
                             char* __restrict__ xqp,
                             int* __restrict__ wq4) {
    if (blockIdx.x < 256) {
        const int rb = blockIdx.x;
        const int wv = threadIdx.x >> 6;
        const int l  = threadIdx.x & 63;
        const int row = rb * 16 + (l & 15);
        const float sc = 1.0f / xsinv[row];          // == 127/rowmax (exact-rounded div)
        const float* xr = x + (size_t)row * K_DIM + ((l >> 4) << 4);
        for (int kb = wv; kb < 64; kb += 4) {
            const float4* p = (const float4*)(xr + kb * 64);
            float4 v0 = p[0], v1 = p[1], v2 = p[2], v3 = p[3];
            int4 o;
            o.x = pack4(v0.x, v0.y, v0.z, v0.w, sc);
            o.y = pack4(v1.x, v1.y, v1.z, v1.w, sc);
            o.z = pack4(v2.x, v2.y, v2.z, v2.w, sc);
            o.w = pack4(v3.x, v3.y, v3.z, v3.w, sc);
            *(int4*)(xqp + ((size_t)kb << 18) + ((size_t)rb << 10) + (size_t)l * 16) = o;
        }
    } else {
        const float wscale = 127.0f / __uint_as_float(mb[0]);
        int tid = (blockIdx.x - 256) * blockDim.x + threadIdx.x;
        const int stride = 2048 * 256;
        const int n4 = (N_DIM * K_DIM) / 4;
        const float4* w4 = (const float4*)w;
        for (int i = tid; i < n4; i += stride) {
            float4 a = w4[i];
            int w0 = (int)fminf(fmaxf(truncf(a.x * wscale), -127.f), 127.f);
            int w1 = (int)fminf(fmaxf(truncf(a.y * wscale), -127.f), 127.f);
            int w2 = (int)fminf(fmaxf(truncf(a.z * wscale), -127.f), 127.f);
            int w3 = (int)fminf(fmaxf(truncf(a.w * wscale), -127.f), 127.f);
            wq4[i] = (w0 & 0xff) | ((w1 & 0xff) << 8) | ((w2 & 0xff) << 16) | (w3 << 24);
        }
    }
}

// ---- Kernel 3: 256x256 i8 GEMM. A from global PANELS (contiguous 1KB wave loads,
// software-prefetched 1 tile ahead on the VMEM pipe); B staged in LDS (64KB dbuf,
// XOR-swizzled, conflict-free). One barrier per K-tile. MFMA covers both pipes.
#define BAR()   __builtin_amdgcn_s_barrier()
#define FENCE() __builtin_amdgcn_sched_barrier(0)

#define MFMA_I8(ACC, AF, BF) \
    asm("v_mfma_i32_16x16x64_i8 %0, %1, %2, %0" : "+v"(ACC) : "v"(AF), "v"(BF))

__global__ __launch_bounds__(512, 2) void gemm_i8(
    const char* __restrict__ A,      // xqp panels
    const char* __restrict__ B,      // wq row-major
    const unsigned int* __restrict__ mb,
    const float* __restrict__ xsinv,
    const float* __restrict__ bias,
    float* __restrict__ C)
{
    __shared__ __align__(16) char sM[65536];   // B only: buf0 @0, buf1 @32768

    int bid = (blockIdx.x & 7) * 32 + (blockIdx.x >> 3);   // XCD-bijective (nwg=256)
    const int bm = bid >> 4;
    const int bn = bid & 15;

    const int t    = threadIdx.x;
    const int wave = t >> 6;
    const int lane = t & 63;
    const int wm   = wave >> 2;     // 0..1
    const int wn   = wave & 3;      // 0..3

    i32x4 acc[2][2][4][2] = {};     // [h][g][mi][ni]

    // B LDS-read bases (swizzle folded: row&7 == lane&7 for all row-blocks used)
    const int chunk = (((lane >> 4) << 4) ^ ((lane & 7) << 4));
    const int lbB0 = ((lane & 15) << 7) + chunk + wn * 4096;
    const int lbB1 = lbB0 ^ 64;

    // B staging: thread t owns linear LDS slot t*16 (+8192 for 2nd 64-row block);
    // source chunk pre-swizzled so LDS[row][c] = SRC[row][c^(row&7)].
    const int srow = t >> 3;
    const int cch  = (t & 7) ^ (srow & 7);
    const char* Bbase = B + (size_t)(bn * 256 + srow) * K_DIM + cch * 16;
    const int wave_lds = wave * 1024;

    // A panel base: frag(H,mi,kk of K-tile KT) at Apan + (2*KT+kk)<<18 + (H*8+mi)*1024
    const char* Apan = A + ((size_t)(bm * 16 + wm * 4) << 10) + (size_t)lane * 16;

#define STAGEB(H, KT, BUF) do {                                                         \
        const char* _s = Bbase + (H) * (128 * K_DIM) + ((KT) << 7);                     \
        char* _d = sM + (BUF) * 32768 + (H) * 16384 + wave_lds;                         \
        __builtin_amdgcn_global_load_lds(                                               \
            (const __attribute__((address_space(1))) void*)_s,                          \
            (__attribute__((address_space(3))) void*)_d, 16, 0, 0);                     \
        __builtin_amdgcn_global_load_lds(                                               \
            (const __attribute__((address_space(1))) void*)(_s + (size_t)64 * K_DIM),   \
            (__attribute__((address_space(3))) void*)(_d + 8192), 16, 0, 0);            \
    } while(0)

    // A-frags for row-half H of K-tile KT: 8 x contiguous-1KB global_load_dwordx4
#define LDAG(H, KT, AF) do {                                                            \
        _Pragma("unroll") for (int mi = 0; mi < 4; ++mi)                                \
        _Pragma("unroll") for (int kk = 0; kk < 2; ++kk)                                \
            AF[mi][kk] = *(const i32x4*)(Apan + ((size_t)(2*(KT)+kk) << 18)             \
                                              + (size_t)((H)*8 + mi) * 1024);           \
    } while(0)

#define LDB(G, BUF, BF) do {                                                            \
        _Pragma("unroll") for (int ni = 0; ni < 2; ++ni) {                              \
            BF[ni][0] = *(const i32x4*)(sM + (BUF)*32768 + (G)*16384 + ni*2048 + lbB0); \
            BF[ni][1] = *(const i32x4*)(sM + (BUF)*32768 + (G)*16384 + ni*2048 + lbB1); \
        }                                                                               \
    } while(0)

    // one C-quadrant x K=128: 16 MFMA, kk-outer (8 indep accs between acc reuse)
#define MMAQ(H, G, AF, BF)                                                              \
        _Pragma("unroll") for (int kk = 0; kk < 2; ++kk)                                \
        _Pragma("unroll") for (int mi = 0; mi < 4; ++mi)                                \
        _Pragma("unroll") for (int ni = 0; ni < 2; ++ni)                                \
            MFMA_I8(acc[H][G][mi][ni], AF[mi][kk], BF[ni][kk]);

    i32x4 af0[4][2], af1[4][2], bf0[2][2], bf1[2][2];

    // Prologue: stage B tile0 -> buf0 (4 vmem-lds, oldest), A tile0 frags (16 loads).
    STAGEB(0, 0, 0);
    STAGEB(1, 0, 0);
    LDAG(0, 0, af0);
    LDAG(1, 0, af1);
    asm volatile("s_waitcnt vmcnt(16)");   // drain stages; af stay in flight
    BAR();
    FENCE();

    // One K-tile: B from buf BUF; stage B(KN)->OBUF; prefetch A(KN) after last use.
#define TILE(BUF, OBUF, KN) do {                                                        \
        STAGEB(0, KN, OBUF);                                                            \
        STAGEB(1, KN, OBUF);                     /* 4 vmem-lds, oldest this tile */     \
        LDB(0, BUF, bf0); LDB(1, BUF, bf1);      /* 8 ds_read */                        \
        FENCE();                                                                        \
        __builtin_amdgcn_s_setprio(1);                                                  \
        MMAQ(0, 0, af0, bf0);                                                           \
        MMAQ(0, 1, af0, bf1);                                                           \
        __builtin_amdgcn_s_setprio(0);                                                  \
        FENCE();                                                                        \
        LDAG(0, KN, af0);                        /* reload af0: next use 1300cy away */ \
        FENCE();                                                                        \
        __builtin_amdgcn_s_setprio(1);                                                  \
        MMAQ(1, 1, af1, bf1);                                                           \
        MMAQ(1, 0, af1, bf0);                                                           \
        __builtin_amdgcn_s_setprio(0);                                                  \
        FENCE();                                                                        \
        LDAG(1, KN, af1);                                                               \
        asm volatile("s_waitcnt vmcnt(16)");     /* drain this tile's 4 B-stages */     \
        BAR();                                                                          \
        FENCE();                                                                        \
    } while(0)

    for (int it = 0; it < 16; ++it) {
        TILE(0, 1, (2 * it + 1) & 31);
        TILE(1, 0, (2 * it + 2) & 31);
    }

    asm volatile("s_waitcnt vmcnt(0)");   // drain tail

    const float wdq = __uint_as_float(mb[0]) * (1.0f / 127.0f);

    // Epilogue: D layout (m89): col = lane&15, row = (lane>>4)*4 + reg.
    // C = acc * (wdq * xsinv[row]) + bias[col]
    #pragma unroll
    for (int h = 0; h < 2; ++h)
    #pragma unroll
    for (int mi = 0; mi < 4; ++mi) {
        const int grow0 = bm * 256 + h * 128 + wm * 64 + mi * 16 + (lane >> 4) * 4;
        float rs[4];
        #pragma unroll
        for (int rg = 0; rg < 4; ++rg) rs[rg] = xsinv[grow0 + rg] * wdq;
        #pragma unroll
        for (int g = 0; g < 2; ++g)
        #pragma unroll
        for (int ni = 0; ni < 2; ++ni) {
            const int gcol = bn * 256 + g * 128 + wn * 32 + ni * 16 + (lane & 15);
            const float bv = bias[gcol];
            #pragma unroll
            for (int rg = 0; rg < 4; ++rg)
                C[(size_t)(grow0 + rg) * N_DIM + gcol] =
                    (float)acc[h][g][mi][ni][rg] * rs[rg] + bv;
        }
    }

#undef STAGEB
#undef LDAG
#undef LDB
#undef MMAQ
#undef TILE
}

extern "C" void kernel_launch(void* const* d_in, const int* in_sizes, int n_in,
                              void* d_out, int out_size, void* d_ws, size_t ws_size,
                              hipStream_t stream) {
    const float* x    = (const float*)d_in[0];   // [4096, 4096]
    const float* w    = (const float*)d_in[1];   // [4096, 4096]
    const float* bias = (const float*)d_in[2];   // [4096]
    float* out = (float*)d_out;

    unsigned int* maxbits = (unsigned int*)d_ws;             // [0]=wmax bits
    float* xsinv = (float*)((char*)d_ws + 1024);             // [4096] f32
    char*  xqp   = (char*)d_ws + 17408;                      // 16 MB panels (1KB-aligned)
    char*  wq    = (char*)d_ws + 17408 + (size_t)M_DIM * K_DIM;

    hipMemsetAsync(d_ws, 0, 8, stream);

    rowmax_kernel<<<4096 + 1024, 256, 0, stream>>>(w, x, maxbits, xsinv);
    quant_kernel<<<256 + 2048, 256, 0, stream>>>(w, x, maxbits, xsinv, xqp, (int*)wq);

    const int grid = (M_DIM / 256) * (N_DIM / 256);  // 256
    gemm_i8<<<grid, 512, 0, stream>>>(xqp, wq, maxbits, xsinv, bias, out);
}